// Round 1
// baseline (37.136 us; speedup 1.0000x reference)
//
#include <hip/hip_runtime.h>
#include <math.h>

// Problem constants (from reference: inputs (128, 64, 64, 32) fp32)
#define BB 128
#define NN 64
#define DD 2048            // 64*32
#define ROWS (BB * NN)     // 8192
#define NCHUNK 4           // colsum: D split into 4 chunks of 512
#define NBLK2 (BB * NCHUNK)

__device__ __forceinline__ float wave_reduce_sum(float v) {
    #pragma unroll
    for (int off = 32; off > 0; off >>= 1)
        v += __shfl_down(v, off, 64);
    return v;
}

// Kernel 1: per-row sumsq -> inv_r, d_term. One block per row, 256 threads,
// each thread loads 2 float4 (16B/lane coalesced).
__global__ __launch_bounds__(256) void row_norm_kernel(
        const float* __restrict__ x,
        float* __restrict__ inv_r,
        float* __restrict__ d_term) {
    const int row = blockIdx.x;
    const int t = threadIdx.x;
    const float4* p = reinterpret_cast<const float4*>(x + (size_t)row * DD);
    float4 a = p[t];
    float4 b = p[t + 256];
    float s = a.x * a.x + a.y * a.y + a.z * a.z + a.w * a.w
            + b.x * b.x + b.y * b.y + b.z * b.z + b.w * b.w;
    s = wave_reduce_sum(s);
    __shared__ float red[4];
    const int lane = t & 63, wid = t >> 6;
    if (lane == 0) red[wid] = s;
    __syncthreads();
    if (t == 0) {
        float ss = red[0] + red[1] + red[2] + red[3];
        float r = fmaxf(sqrtf(ss), 1e-12f);
        float inv = 1.0f / r;
        inv_r[row] = inv;
        d_term[row] = ss * inv * inv;   // == ||att_row||^2
    }
}

// Kernel 2: per-batch column sums v[d] = sum_n x[b][n][d] * inv_r[b*N+n],
// then block-reduce sum_d v^2. Grid = B * NCHUNK blocks; each thread owns
// 2 consecutive d columns (float2).
__global__ __launch_bounds__(256) void colsum_kernel(
        const float* __restrict__ x,
        const float* __restrict__ inv_r,
        float* __restrict__ s_partial) {
    const int b = blockIdx.x >> 2;          // / NCHUNK
    const int c = blockIdx.x & (NCHUNK - 1);
    const int t = threadIdx.x;
    const int d0 = c * (DD / NCHUNK) + t * 2;   // chunk of 512 columns

    __shared__ float invs[NN];
    if (t < NN) invs[t] = inv_r[b * NN + t];
    __syncthreads();

    const float2* x2 = reinterpret_cast<const float2*>(x);
    const size_t base = ((size_t)b * NN * DD + d0) >> 1;  // in float2 units
    float vx = 0.f, vy = 0.f;
    #pragma unroll
    for (int n = 0; n < NN; ++n) {
        float2 a = x2[base + (size_t)n * (DD / 2)];
        vx = fmaf(a.x, invs[n], vx);
        vy = fmaf(a.y, invs[n], vy);
    }
    float p = vx * vx + vy * vy;
    p = wave_reduce_sum(p);
    __shared__ float red[4];
    const int lane = t & 63, wid = t >> 6;
    if (lane == 0) red[wid] = p;
    __syncthreads();
    if (t == 0)
        s_partial[blockIdx.x] = red[0] + red[1] + red[2] + red[3];
}

// Kernel 3: final double-precision accumulation and loss.
__global__ __launch_bounds__(256) void finalize_kernel(
        const float* __restrict__ d_term,
        const float* __restrict__ s_partial,
        float* __restrict__ out) {
    const int t = threadIdx.x;
    double acc_d = 0.0, acc_s = 0.0;
    for (int i = t; i < ROWS; i += 256) acc_d += (double)d_term[i];
    for (int i = t; i < NBLK2; i += 256) acc_s += (double)s_partial[i];
    __shared__ double sd[256];
    __shared__ double ss[256];
    sd[t] = acc_d;
    ss[t] = acc_s;
    __syncthreads();
    #pragma unroll
    for (int off = 128; off > 0; off >>= 1) {
        if (t < off) { sd[t] += sd[t + off]; ss[t] += ss[t + off]; }
        __syncthreads();
    }
    if (t == 0)
        out[0] = (float)((ss[0] - sd[0]) / (double)BB);
}

extern "C" void kernel_launch(void* const* d_in, const int* in_sizes, int n_in,
                              void* d_out, int out_size, void* d_ws, size_t ws_size,
                              hipStream_t stream) {
    const float* x = (const float*)d_in[0];
    float* out = (float*)d_out;

    float* inv_r    = (float*)d_ws;          // 8192 floats
    float* d_term   = inv_r + ROWS;          // 8192 floats
    float* s_part   = d_term + ROWS;         // 512 floats

    row_norm_kernel<<<ROWS, 256, 0, stream>>>(x, inv_r, d_term);
    colsum_kernel<<<NBLK2, 256, 0, stream>>>(x, inv_r, s_part);
    finalize_kernel<<<1, 256, 0, stream>>>(d_term, s_part, out);
}